// Round 2
// baseline (2155.734 us; speedup 1.0000x reference)
//
#include <hip/hip_runtime.h>

// VectorQuantizer: z[32768,256] f32, W[8192,256] f32 (|W| <= 1/8192).
// np ref (fp32): d = (sum(z^2,axis1,keepdims) + sum(W^2,axis1)) - 2*einsum(z,W)
//                idx = argmin(d, axis=1)  [first-min tie-break]
// Scores are ~256 in magnitude -> fp32-quantized to ~3e-5 grid; top-2 gaps
// average 5.6e-4, so ~4% of rows have quantized ties. We must REPLICATE the
// fp32 arithmetic (incl. numpy pairwise-sum order for s_z/s_w and the final
// rounding at magnitude ~256), then tie-break by lowest index.

constexpr int N = 32768;
constexpr int K = 8192;
constexpr int D = 256;

constexpr int MT = 32;    // z rows per block
constexpr int KT = 128;   // codes per k-tile
constexpr int DC = 64;    // d-chunk staged per step

// ---------------------------------------------------- row sum-of-squares ---
// Replicates np.sum(x**2, axis=1) for 256-wide rows with numpy's pairwise
// order: split 128+128; each half: 8 accumulators r[j] = sum of a[j::8],
// combined ((r0+r1)+(r2+r3))+((r4+r5)+(r6+r7)); total = half0 + half1.
// Squares are rounded individually (stored to LDS before summation).
__global__ __launch_bounds__(256) void rowsq_pairwise(const float* __restrict__ X,
                                                      float* __restrict__ out) {
    __shared__ float sq[64][257];   // +1 pad: column reads conflict-free
    const int t = threadIdx.x;
    const size_t base = (size_t)blockIdx.x * 64 * D;
#pragma unroll
    for (int it = 0; it < 16; ++it) {
        int q = it * 256 + t;       // 0..4095 quad id
        int r = q >> 6;             // row 0..63
        int c = q & 63;             // float4 within row
        float4 v = ((const float4*)(X + base + (size_t)r * D))[c];
        sq[r][4 * c + 0] = v.x * v.x;
        sq[r][4 * c + 1] = v.y * v.y;
        sq[r][4 * c + 2] = v.z * v.z;
        sq[r][4 * c + 3] = v.w * v.w;
    }
    __syncthreads();
    if (t < 64) {
        const float* p = sq[t];
        float tot = 0.f;
        for (int h = 0; h < 2; ++h) {
            const float* ph = p + h * 128;
            float r8[8];
#pragma unroll
            for (int j = 0; j < 8; ++j) r8[j] = ph[j];
            for (int i = 8; i < 128; i += 8)
#pragma unroll
                for (int j = 0; j < 8; ++j) r8[j] += ph[i + j];
            float res = ((r8[0] + r8[1]) + (r8[2] + r8[3])) +
                        ((r8[4] + r8[5]) + (r8[6] + r8[7]));
            tot = (h == 0) ? res : (tot + res);
        }
        out[blockIdx.x * 64 + t] = tot;
    }
}

// ------------------------------------------------------------- main --------
__global__ __launch_bounds__(256, 2) void vq_main(const float* __restrict__ Z,
                                                  const float* __restrict__ W,
                                                  const float* __restrict__ s_z,
                                                  const float* __restrict__ s_w,
                                                  int* __restrict__ idx_out) {
    __shared__ float zs[D][MT + 4];    // [d][r]
    __shared__ float wsh[DC][KT + 4];  // [dd][kk]
    __shared__ float swh[KT];
    __shared__ float red_v[MT][32];
    __shared__ int   red_k[MT][32];

    const int t = threadIdx.x;
    const int n0 = blockIdx.x * MT;
    const int tr = t & 7;   // rows tr*4 .. tr*4+3
    const int tk = t >> 3;  // cols tk*4 .. tk*4+3

    float sz4[4];
#pragma unroll
    for (int i = 0; i < 4; ++i) sz4[i] = s_z[n0 + tr * 4 + i];

    // stage z tile transposed: zs[d][r] = Z[n0+r][d]
    {
        int q = t & 63;
        int rw = t >> 6;
#pragma unroll
        for (int i = 0; i < 8; ++i) {
            int r = rw + 4 * i;
            float4 v = ((const float4*)(Z + (size_t)(n0 + r) * D))[q];
            zs[4 * q + 0][r] = v.x;
            zs[4 * q + 1][r] = v.y;
            zs[4 * q + 2][r] = v.z;
            zs[4 * q + 3][r] = v.w;
        }
    }

    float minv[4] = {1e30f, 1e30f, 1e30f, 1e30f};
    int   mink[4] = {0, 0, 0, 0};

    for (int kt = 0; kt < K; kt += KT) {
        float acc[4][4];
#pragma unroll
        for (int i = 0; i < 4; ++i)
#pragma unroll
            for (int j = 0; j < 4; ++j) acc[i][j] = 0.f;

#pragma unroll 1
        for (int dc = 0; dc < D; dc += DC) {
            __syncthreads();
            {
                int kk = t >> 1;
                int h = t & 1;
                const float* wr = W + (size_t)(kt + kk) * D + dc + h * 32;
#pragma unroll
                for (int j = 0; j < 8; ++j) {
                    float4 v = ((const float4*)wr)[j];
                    int d0 = h * 32 + 4 * j;
                    wsh[d0 + 0][kk] = v.x;
                    wsh[d0 + 1][kk] = v.y;
                    wsh[d0 + 2][kk] = v.z;
                    wsh[d0 + 3][kk] = v.w;
                }
            }
            if (dc == 0 && t < KT) swh[t] = s_w[kt + t];
            __syncthreads();
#pragma unroll 8
            for (int dd = 0; dd < DC; ++dd) {
                float4 a = *(const float4*)&zs[dc + dd][tr * 4];
                float4 b = *(const float4*)&wsh[dd][tk * 4];
                float av[4] = {a.x, a.y, a.z, a.w};
                float bv[4] = {b.x, b.y, b.z, b.w};
#pragma unroll
                for (int i = 0; i < 4; ++i)
#pragma unroll
                    for (int j = 0; j < 4; ++j)
                        acc[i][j] = fmaf(av[i], bv[j], acc[i][j]);
            }
        }
        // epilogue: d = fl(fl(s_z + s_w) - 2*dot); running argmin, lowest k on ties
#pragma unroll
        for (int j = 0; j < 4; ++j) {
            float sw = swh[tk * 4 + j];
            int kg = kt + tk * 4 + j;
#pragma unroll
            for (int i = 0; i < 4; ++i) {
                float t1 = sz4[i] + sw;                   // fp32 round at ~256
                float dval = t1 - 2.0f * acc[i][j];       // fp32 round at ~256
                if (dval < minv[i]) { minv[i] = dval; mink[i] = kg; }
            }
        }
    }

    __syncthreads();
#pragma unroll
    for (int i = 0; i < 4; ++i) {
        red_v[tr * 4 + i][tk] = minv[i];
        red_k[tr * 4 + i][tk] = mink[i];
    }
    __syncthreads();
    if (t < MT) {
        float bv = red_v[t][0];
        int bk = red_k[t][0];
        for (int s = 1; s < 32; ++s) {
            float v = red_v[t][s];
            int kk2 = red_k[t][s];
            if (v < bv || (v == bv && kk2 < bk)) { bv = v; bk = kk2; }
        }
        idx_out[n0 + t] = bk;
    }
}

// ----------------------------------------------------------- outputs -------
__global__ __launch_bounds__(256) void out_kernel(const float* __restrict__ W,
                                                  const int* __restrict__ idx,
                                                  float* __restrict__ zq,
                                                  float* __restrict__ idx_f,
                                                  float* __restrict__ loss) {
    int r = blockIdx.x * 4 + (threadIdx.x >> 6);
    int lane = threadIdx.x & 63;
    int k = idx[r];
    float4 v = ((const float4*)(W + (size_t)k * D))[lane];
    ((float4*)(zq + (size_t)r * D))[lane] = v;
    if (lane == 0) {
        idx_f[r] = (float)k;
        loss[r] = 0.f;
    }
}

// ------------------------------------------------------------ launch -------
extern "C" void kernel_launch(void* const* d_in, const int* in_sizes, int n_in,
                              void* d_out, int out_size, void* d_ws, size_t ws_size,
                              hipStream_t stream) {
    const float* Z = (const float*)d_in[0];
    const float* W = (const float*)d_in[1];

    float* zq    = (float*)d_out;                 // [N, D]
    float* idx_f = zq + (size_t)N * D;            // [N] as float
    float* loss  = idx_f + N;                     // [N]

    float* s_w   = (float*)d_ws;                  // [K]
    float* s_z   = s_w + K;                       // [N]
    int*   idx_i = (int*)(s_z + N);               // [N]

    rowsq_pairwise<<<K / 64, 256, 0, stream>>>(W, s_w);
    rowsq_pairwise<<<N / 64, 256, 0, stream>>>(Z, s_z);
    vq_main<<<N / MT, 256, 0, stream>>>(Z, W, s_z, s_w, idx_i);
    out_kernel<<<N / 4, 256, 0, stream>>>(W, idx_i, zq, idx_f, loss);
}

// Round 3
// 743.137 us; speedup vs baseline: 2.9009x; 2.9009x over previous
//
#include <hip/hip_runtime.h>
#include <stdint.h>

// VectorQuantizer via bf16-MFMA screen + exact fp32 rescore.
// Exact score replication (proven in R2): d = fl(fl(s_z_pairwise + s_w_pairwise) - 2*dot_f32),
// argmin with lowest-index tie-break. Screen: m = s_w[k] - 2*dot_bf16 (row-const s_z dropped);
// |screen - exact| <= bf16 err (~2e-5) + quant (~4.6e-5) << MARGIN=3e-4.

constexpr int N = 32768;
constexpr int K = 8192;
constexpr int D = 256;
constexpr int CAP = 24;
#define MARGIN 3.0e-4f

typedef __attribute__((ext_vector_type(8))) short short8v;
typedef __attribute__((ext_vector_type(4))) float float4v;

__device__ inline short f2bf(float f) {            // RNE float->bf16
    unsigned u = __float_as_uint(f);
    unsigned r = (u + 0x7FFFu + ((u >> 16) & 1u)) >> 16;
    return (short)r;
}
__device__ inline unsigned encf(float x) {         // order-preserving f32->u32
    unsigned u = __float_as_uint(x);
    return (u & 0x80000000u) ? ~u : (u | 0x80000000u);
}
__device__ inline float decf(unsigned e) {
    unsigned u = (e & 0x80000000u) ? (e & 0x7FFFFFFFu) : ~e;
    return __uint_as_float(u);
}
__device__ inline void load_lds16(const void* g, void* l) {
    __builtin_amdgcn_global_load_lds(
        (const __attribute__((address_space(1))) void*)g,
        (__attribute__((address_space(3))) void*)l, 16, 0, 0);
}

// ---------------------------------------------------- row sum-of-squares ---
// numpy pairwise replication (PROVEN in R2) — do not touch.
__global__ __launch_bounds__(256) void rowsq_pairwise(const float* __restrict__ X,
                                                      float* __restrict__ out) {
    __shared__ float sq[64][257];
    const int t = threadIdx.x;
    const size_t base = (size_t)blockIdx.x * 64 * D;
#pragma unroll
    for (int it = 0; it < 16; ++it) {
        int q = it * 256 + t;
        int r = q >> 6;
        int c = q & 63;
        float4 v = ((const float4*)(X + base + (size_t)r * D))[c];
        sq[r][4 * c + 0] = v.x * v.x;
        sq[r][4 * c + 1] = v.y * v.y;
        sq[r][4 * c + 2] = v.z * v.z;
        sq[r][4 * c + 3] = v.w * v.w;
    }
    __syncthreads();
    if (t < 64) {
        const float* p = sq[t];
        float tot = 0.f;
        for (int h = 0; h < 2; ++h) {
            const float* ph = p + h * 128;
            float r8[8];
#pragma unroll
            for (int j = 0; j < 8; ++j) r8[j] = ph[j];
            for (int i = 8; i < 128; i += 8)
#pragma unroll
                for (int j = 0; j < 8; ++j) r8[j] += ph[i + j];
            float res = ((r8[0] + r8[1]) + (r8[2] + r8[3])) +
                        ((r8[4] + r8[5]) + (r8[6] + r8[7]));
            tot = (h == 0) ? res : (tot + res);
        }
        out[blockIdx.x * 64 + t] = tot;
    }
}

// ------------------------------------------------------------- repack ------
// Xf fragment order: [b(128 rows)][r16(8)][s(8)][lane(64)][8 bf16], 1KB chunks.
// element = X[b*128 + r16*16 + (lane&15)][s*32 + (lane>>4)*8 + j]  (A/B operand layout)
__global__ __launch_bounds__(256) void repack_frag(const float* __restrict__ X,
                                                   short* __restrict__ Xf) {
    const int g = blockIdx.x * 4 + (threadIdx.x >> 6);
    const int lane = threadIdx.x & 63;
    const int b = g >> 6, c = g & 63, r16 = c >> 3, s = c & 7;
    const int row = b * 128 + r16 * 16 + (lane & 15);
    const int d0 = s * 32 + ((lane >> 4) << 3);
    const float* src = X + (size_t)row * D + d0;
    float4 v0 = ((const float4*)src)[0];
    float4 v1 = ((const float4*)src)[1];
    short8v o;
    o[0] = f2bf(v0.x); o[1] = f2bf(v0.y); o[2] = f2bf(v0.z); o[3] = f2bf(v0.w);
    o[4] = f2bf(v1.x); o[5] = f2bf(v1.y); o[6] = f2bf(v1.z); o[7] = f2bf(v1.w);
    *(short8v*)(Xf + (size_t)g * 512 + lane * 8) = o;
}

// ------------------------------------------------------------- screen ------
// block: 256 thr = 4 waves; 128 z-rows resident (A, 64KB); scan 64 ktiles of
// 128 W-cols (B, 64KB/tile). Wave-tile 64x64 = 4x4 of mfma 16x16x32 bf16.
__global__ __launch_bounds__(256, 1) void vq_screen(
    const short* __restrict__ Zf, const short* __restrict__ Wf,
    const float* __restrict__ s_w, const float* __restrict__ s_z,
    const float* __restrict__ Z, const float* __restrict__ W,
    int* __restrict__ idx_out)
{
    __shared__ short As[32768];
    __shared__ short Bs[32768];
    __shared__ unsigned smin[128];           // encoded prefix row-min
    __shared__ unsigned ccnt[128];
    __shared__ unsigned candk_s[128][CAP];
    __shared__ float    candm_s[128][CAP];
    __shared__ float    swh[128];

    const int t = threadIdx.x;
    const int w = t >> 6;
    const int lane = t & 63;
    const int rhalf = w & 1;
    const int chalf = w >> 1;

    if (t < 128) { smin[t] = 0xFFFFFFFFu; ccnt[t] = 0u; }

    // stage A once: 64 chunks x 1KB
    {
        const short* gA = Zf + (size_t)blockIdx.x * 32768 + (size_t)w * 16 * 512 + lane * 8;
        short* lA = As + w * 16 * 512;
#pragma unroll
        for (int i = 0; i < 16; ++i)
            load_lds16(gA + i * 512, lA + i * 512);
    }

    float slotmin[16];
#pragma unroll
    for (int i = 0; i < 16; ++i) slotmin[i] = 1e30f;

    const int r0 = rhalf * 64 + ((lane >> 4) << 2);  // + 16*i + reg
    const int c0 = chalf * 64 + (lane & 15);         // + 16*j

    for (int kt = 0; kt < 64; ++kt) {
        __syncthreads();                             // B readers done
        {
            const short* gB = Wf + ((size_t)kt * 64 + w * 16) * 512 + lane * 8;
            short* lB = Bs + w * 16 * 512;
#pragma unroll
            for (int i = 0; i < 16; ++i)
                load_lds16(gB + i * 512, lB + i * 512);
        }
        if (t < 128) swh[t] = s_w[kt * 128 + t];
        __syncthreads();                             // staging drained (vmcnt0)

        float4v acc[4][4];
#pragma unroll
        for (int i = 0; i < 4; ++i)
#pragma unroll
            for (int j = 0; j < 4; ++j)
#pragma unroll
                for (int r = 0; r < 4; ++r) acc[i][j][r] = 0.f;

#pragma unroll
        for (int s = 0; s < 8; ++s) {
            short8v af[4], bf[4];
#pragma unroll
            for (int i = 0; i < 4; ++i)
                af[i] = *(const short8v*)&As[((rhalf * 4 + i) * 8 + s) * 512 + lane * 8];
#pragma unroll
            for (int j = 0; j < 4; ++j)
                bf[j] = *(const short8v*)&Bs[((chalf * 4 + j) * 8 + s) * 512 + lane * 8];
#pragma unroll
            for (int i = 0; i < 4; ++i)
#pragma unroll
                for (int j = 0; j < 4; ++j)
                    acc[i][j] = __builtin_amdgcn_mfma_f32_16x16x32_bf16(af[i], bf[j], acc[i][j], 0, 0, 0);
        }

        // epilogue: m = s_w - 2*dot; shared prefix-min; margin recording
#pragma unroll
        for (int i = 0; i < 4; ++i) {
#pragma unroll
            for (int r = 0; r < 4; ++r) {
                const int rowL = r0 + 16 * i + r;
                float m0 = fmaf(-2.f, acc[i][0][r], swh[c0]);
                float m1 = fmaf(-2.f, acc[i][1][r], swh[c0 + 16]);
                float m2 = fmaf(-2.f, acc[i][2][r], swh[c0 + 32]);
                float m3 = fmaf(-2.f, acc[i][3][r], swh[c0 + 48]);
                float mj = fminf(fminf(m0, m1), fminf(m2, m3));
                const int sl = i * 4 + r;
                if (mj < slotmin[sl]) {
                    slotmin[sl] = mj;
                    atomicMin(&smin[rowL], encf(mj));
                }
                float thr = decf(smin[rowL]) + MARGIN;
                if (m0 <= thr || m1 <= thr || m2 <= thr || m3 <= thr) {
                    const int kb = kt * 128 + c0;
                    if (m0 <= thr) { unsigned s2 = atomicAdd(&ccnt[rowL], 1u); if (s2 < CAP) { candk_s[rowL][s2] = kb;      candm_s[rowL][s2] = m0; } }
                    if (m1 <= thr) { unsigned s2 = atomicAdd(&ccnt[rowL], 1u); if (s2 < CAP) { candk_s[rowL][s2] = kb + 16; candm_s[rowL][s2] = m1; } }
                    if (m2 <= thr) { unsigned s2 = atomicAdd(&ccnt[rowL], 1u); if (s2 < CAP) { candk_s[rowL][s2] = kb + 32; candm_s[rowL][s2] = m2; } }
                    if (m3 <= thr) { unsigned s2 = atomicAdd(&ccnt[rowL], 1u); if (s2 < CAP) { candk_s[rowL][s2] = kb + 48; candm_s[rowL][s2] = m3; } }
                }
            }
        }
    }

    __syncthreads();
    // exact fp32 rescore of surviving candidates (replicated epilogue)
    if (t < 128) {
        const int gr = blockIdx.x * 128 + t;
        unsigned cnt = ccnt[t];
        if (cnt > CAP) {
            idx_out[gr] = (int)0x80000000u;          // overflow -> fallback
        } else {
            const float thr = decf(smin[t]) + MARGIN;
            const float sz = s_z[gr];
            const float4* zr = (const float4*)(Z + (size_t)gr * D);
            float best = 1e30f; int bk = 0x7FFFFFFF;
            for (unsigned c2 = 0; c2 < cnt; ++c2) {
                if (candm_s[t][c2] > thr) continue;
                const int k = (int)candk_s[t][c2];
                const float4* wr = (const float4*)(W + (size_t)k * D);
                float ax = 0.f, ay = 0.f, az = 0.f, aw = 0.f;
                for (int q = 0; q < 64; ++q) {
                    float4 zv = zr[q], wv = wr[q];
                    ax = fmaf(zv.x, wv.x, ax);
                    ay = fmaf(zv.y, wv.y, ay);
                    az = fmaf(zv.z, wv.z, az);
                    aw = fmaf(zv.w, wv.w, aw);
                }
                float dot = (ax + ay) + (az + aw);
                float dd = (sz + s_w[k]) - 2.0f * dot;
                if (dd < best || (dd == best && k < bk)) { best = dd; bk = k; }
            }
            idx_out[gr] = bk;
        }
    }
}

// ------------------------------------------------------------ fallback -----
__global__ __launch_bounds__(256) void vq_fallback(
    const float* __restrict__ Z, const float* __restrict__ W,
    const float* __restrict__ s_z, const float* __restrict__ s_w,
    int* __restrict__ idx)
{
    __shared__ float rv[256];
    __shared__ int   rk[256];
    const int t = threadIdx.x;
    const int base = blockIdx.x * 128;
    for (int r = 0; r < 128; ++r) {
        if (idx[base + r] >= 0) continue;            // uniform per block
        const int gr = base + r;
        const float sz = s_z[gr];
        const float4* zr = (const float4*)(Z + (size_t)gr * D);
        float best = 1e30f; int bk = 0x7FFFFFFF;
        for (int k = t; k < K; k += 256) {
            const float4* wr = (const float4*)(W + (size_t)k * D);
            float ax = 0.f, ay = 0.f, az = 0.f, aw = 0.f;
            for (int q = 0; q < 64; ++q) {
                float4 zv = zr[q], wv = wr[q];
                ax = fmaf(zv.x, wv.x, ax);
                ay = fmaf(zv.y, wv.y, ay);
                az = fmaf(zv.z, wv.z, az);
                aw = fmaf(zv.w, wv.w, aw);
            }
            float dd = (sz + s_w[k]) - 2.0f * ((ax + ay) + (az + aw));
            if (dd < best || (dd == best && k < bk)) { best = dd; bk = k; }
        }
        rv[t] = best; rk[t] = bk;
        __syncthreads();
        for (int off = 128; off > 0; off >>= 1) {
            if (t < off) {
                float v2 = rv[t + off]; int k2 = rk[t + off];
                if (v2 < rv[t] || (v2 == rv[t] && k2 < rk[t])) { rv[t] = v2; rk[t] = k2; }
            }
            __syncthreads();
        }
        if (t == 0) idx[gr] = rk[0];
        __syncthreads();
    }
}

// ----------------------------------------------------------- outputs -------
__global__ __launch_bounds__(256) void out_kernel(const float* __restrict__ W,
                                                  const int* __restrict__ idx,
                                                  float* __restrict__ zq,
                                                  float* __restrict__ idx_f,
                                                  float* __restrict__ loss) {
    int r = blockIdx.x * 4 + (threadIdx.x >> 6);
    int lane = threadIdx.x & 63;
    int k = idx[r];
    float4 v = ((const float4*)(W + (size_t)k * D))[lane];
    ((float4*)(zq + (size_t)r * D))[lane] = v;
    if (lane == 0) {
        idx_f[r] = (float)k;
        loss[r] = 0.f;
    }
}

// ------------------------------------------------------------ launch -------
extern "C" void kernel_launch(void* const* d_in, const int* in_sizes, int n_in,
                              void* d_out, int out_size, void* d_ws, size_t ws_size,
                              hipStream_t stream) {
    const float* Z = (const float*)d_in[0];
    const float* W = (const float*)d_in[1];

    float* zq    = (float*)d_out;                 // [N, D]
    float* idx_f = zq + (size_t)N * D;            // [N]
    float* loss  = idx_f + N;                     // [N]

    // scratch: bf16 fragment arrays live in the (not-yet-written) zq region
    short* Zf = (short*)d_out;                                  // 16 MB
    short* Wf = (short*)((char*)d_out + (size_t)16 * 1024 * 1024); // 4 MB

    float* s_w   = (float*)d_ws;                  // [K]
    float* s_z   = s_w + K;                       // [N]
    int*   idx_i = (int*)(s_z + N);               // [N]

    repack_frag<<<(N / 128) * 16, 256, 0, stream>>>(Z, Zf);   // 4096 blocks
    repack_frag<<<(K / 128) * 16, 256, 0, stream>>>(W, Wf);   // 1024 blocks
    rowsq_pairwise<<<K / 64, 256, 0, stream>>>(W, s_w);
    rowsq_pairwise<<<N / 64, 256, 0, stream>>>(Z, s_z);
    vq_screen<<<N / 128, 256, 0, stream>>>(Zf, Wf, s_w, s_z, Z, W, idx_i);
    vq_fallback<<<N / 128, 256, 0, stream>>>(Z, W, s_z, s_w, idx_i);
    out_kernel<<<N / 4, 256, 0, stream>>>(W, idx_i, zq, idx_f, loss);
}